// Round 2
// baseline (765.358 us; speedup 1.0000x reference)
//
#include <hip/hip_runtime.h>
#include <hip/hip_bf16.h>
#include <math.h>

#define B_SZ 64
#define NQ   512
#define NV   1024
#define QD   768
#define VD   512
#define HIDD 512

typedef __bf16 bf16x8 __attribute__((ext_vector_type(8)));
typedef float  floatx4 __attribute__((ext_vector_type(4)));

__device__ __forceinline__ void stage8_f32(const float* __restrict__ src, __bf16* dst) {
    float4 f0 = *(const float4*)src;
    float4 f1 = *(const float4*)(src + 4);
    bf16x8 pk;
    pk[0] = (__bf16)f0.x; pk[1] = (__bf16)f0.y; pk[2] = (__bf16)f0.z; pk[3] = (__bf16)f0.w;
    pk[4] = (__bf16)f1.x; pk[5] = (__bf16)f1.y; pk[6] = (__bf16)f1.z; pk[7] = (__bf16)f1.w;
    *(bf16x8*)dst = pk;
}

// C[M,N] = A[M,K] @ W[N,K]^T + bias, output bf16.  64x64 tile, BK=32, 4 waves.
__global__ __launch_bounds__(256) void gemm_proj(
    const float* __restrict__ A, const float* __restrict__ W,
    const float* __restrict__ bias, __bf16* __restrict__ Cout,
    int M, int N, int K)
{
    __shared__ __bf16 As[64 * 32];
    __shared__ __bf16 Bs[64 * 32];
    const int tile_m = blockIdx.x * 64;
    const int tile_n = blockIdx.y * 64;
    const int t    = threadIdx.x;
    const int lane = t & 63;
    const int wave = t >> 6;
    const int wm = (wave >> 1) * 32;
    const int wn = (wave & 1) * 32;
    const int ar = t >> 2;         // staging row 0..63
    const int ac = (t & 3) * 8;    // staging col 0,8,16,24
    const int fr = lane & 15;      // fragment row/col within 16
    const int fo = (lane >> 4) * 8;// fragment k offset

    floatx4 acc[2][2] = {};
    const float* ap = A + (size_t)(tile_m + ar) * K + ac;
    const float* wp = W + (size_t)(tile_n + ar) * K + ac;

    for (int k0 = 0; k0 < K; k0 += 32) {
        stage8_f32(ap + k0, &As[ar * 32 + ac]);
        stage8_f32(wp + k0, &Bs[ar * 32 + ac]);
        __syncthreads();
        bf16x8 af0 = *(const bf16x8*)&As[(wm + fr) * 32 + fo];
        bf16x8 af1 = *(const bf16x8*)&As[(wm + 16 + fr) * 32 + fo];
        bf16x8 bg0 = *(const bf16x8*)&Bs[(wn + fr) * 32 + fo];
        bf16x8 bg1 = *(const bf16x8*)&Bs[(wn + 16 + fr) * 32 + fo];
        acc[0][0] = __builtin_amdgcn_mfma_f32_16x16x32_bf16(af0, bg0, acc[0][0], 0, 0, 0);
        acc[0][1] = __builtin_amdgcn_mfma_f32_16x16x32_bf16(af0, bg1, acc[0][1], 0, 0, 0);
        acc[1][0] = __builtin_amdgcn_mfma_f32_16x16x32_bf16(af1, bg0, acc[1][0], 0, 0, 0);
        acc[1][1] = __builtin_amdgcn_mfma_f32_16x16x32_bf16(af1, bg1, acc[1][1], 0, 0, 0);
        __syncthreads();
    }
    for (int i = 0; i < 2; i++)
        for (int j = 0; j < 2; j++) {
            int col = tile_n + wn + j * 16 + fr;
            float bv = bias[col];
            for (int r = 0; r < 4; r++) {
                int row = tile_m + wm + i * 16 + (lane >> 4) * 4 + r;
                Cout[(size_t)row * N + col] = (__bf16)(acc[i][j][r] + bv);
            }
        }
}

// Per batch: S = Qp[b] @ Vp[b]^T ; E = exp(tanh(S)) -> Eg (bf16); accumulate
// row sums R[b,q] and col sums C[b,v] (fp32, atomic per tile-row/col).
__global__ __launch_bounds__(256) void gemm_h(
    const __bf16* __restrict__ Qp, const __bf16* __restrict__ Vp,
    __bf16* __restrict__ Eg, float* __restrict__ R, float* __restrict__ Csum)
{
    __shared__ __bf16 As[64 * 32];
    __shared__ __bf16 Bs[64 * 32];
    __shared__ float Etile[64 * 65];   // +1 pad: conflict-free row & col sums
    const int b      = blockIdx.z;
    const int tile_q = blockIdx.y * 64;
    const int tile_v = blockIdx.x * 64;
    const int t    = threadIdx.x;
    const int lane = t & 63;
    const int wave = t >> 6;
    const int wm = (wave >> 1) * 32;
    const int wn = (wave & 1) * 32;
    const int ar = t >> 2;
    const int ac = (t & 3) * 8;
    const int fr = lane & 15;
    const int fo = (lane >> 4) * 8;

    const __bf16* Aq = Qp + (size_t)b * NQ * HIDD + (size_t)(tile_q + ar) * HIDD + ac;
    const __bf16* Bv = Vp + (size_t)b * NV * HIDD + (size_t)(tile_v + ar) * HIDD + ac;

    floatx4 acc[2][2] = {};
    for (int k0 = 0; k0 < HIDD; k0 += 32) {
        *(bf16x8*)&As[ar * 32 + ac] = *(const bf16x8*)(Aq + k0);
        *(bf16x8*)&Bs[ar * 32 + ac] = *(const bf16x8*)(Bv + k0);
        __syncthreads();
        bf16x8 af0 = *(const bf16x8*)&As[(wm + fr) * 32 + fo];
        bf16x8 af1 = *(const bf16x8*)&As[(wm + 16 + fr) * 32 + fo];
        bf16x8 bg0 = *(const bf16x8*)&Bs[(wn + fr) * 32 + fo];
        bf16x8 bg1 = *(const bf16x8*)&Bs[(wn + 16 + fr) * 32 + fo];
        acc[0][0] = __builtin_amdgcn_mfma_f32_16x16x32_bf16(af0, bg0, acc[0][0], 0, 0, 0);
        acc[0][1] = __builtin_amdgcn_mfma_f32_16x16x32_bf16(af0, bg1, acc[0][1], 0, 0, 0);
        acc[1][0] = __builtin_amdgcn_mfma_f32_16x16x32_bf16(af1, bg0, acc[1][0], 0, 0, 0);
        acc[1][1] = __builtin_amdgcn_mfma_f32_16x16x32_bf16(af1, bg1, acc[1][1], 0, 0, 0);
        __syncthreads();
    }
    for (int i = 0; i < 2; i++)
        for (int j = 0; j < 2; j++)
            for (int r = 0; r < 4; r++) {
                int row = wm + i * 16 + (lane >> 4) * 4 + r;
                int col = wn + j * 16 + fr;
                Etile[row * 65 + col] = __expf(tanhf(acc[i][j][r]));
            }
    __syncthreads();
    // coalesced bf16 store of the E tile
    for (int idx = t; idx < 4096; idx += 256) {
        int row = idx >> 6, col = idx & 63;
        Eg[((size_t)(b * NQ + tile_q + row)) * NV + tile_v + col] =
            (__bf16)Etile[row * 65 + col];
    }
    if (t < 64) {                 // row sums (over v) -> R
        float s = 0.f;
        for (int j = 0; j < 64; j++) s += Etile[t * 65 + j];
        atomicAdd(&R[b * NQ + tile_q + t], s);
    } else if (t < 128) {         // col sums (over q) -> C
        int c = t - 64;
        float s = 0.f;
        for (int j = 0; j < 64; j++) s += Etile[j * 65 + c];
        atomicAdd(&Csum[b * NV + tile_v + c], s);
    }
}

__global__ __launch_bounds__(256) void recip_k(float* __restrict__ p, int n) {
    int i = blockIdx.x * 256 + threadIdx.x;
    if (i < n) p[i] = 1.0f / p[i];
}

// sv[b,v] = sum_q E[b,q,v] * Rinv[b,q]
__global__ __launch_bounds__(256) void sv_k(const __bf16* __restrict__ E,
                                            const float* __restrict__ Rinv,
                                            float* __restrict__ sv) {
    int b = blockIdx.y;
    int v = blockIdx.x * 256 + threadIdx.x;
    const __bf16* Eb = E + (size_t)b * NQ * NV + v;
    const float* Ri = Rinv + b * NQ;
    float acc = 0.f;
    for (int q = 0; q < NQ; q++) acc += (float)Eb[(size_t)q * NV] * Ri[q];
    sv[b * NV + v] = acc;
}

// sq[b,q] = sum_v E[b,q,v] * Cinv[b,v]   (one block per row)
__global__ __launch_bounds__(256) void sq_k(const __bf16* __restrict__ E,
                                            const float* __restrict__ Cinv,
                                            float* __restrict__ sq) {
    int b = blockIdx.y, q = blockIdx.x, t = threadIdx.x;
    const __bf16* Eb = E + ((size_t)b * NQ + q) * NV;
    const float* Ci = Cinv + b * NV;
    float acc = 0.f;
    for (int v = t; v < NV; v += 256) acc += (float)Eb[v] * Ci[v];
    for (int off = 32; off > 0; off >>= 1) acc += __shfl_down(acc, off);
    __shared__ float red[4];
    if ((t & 63) == 0) red[t >> 6] = acc;
    __syncthreads();
    if (t == 0) sq[b * NQ + q] = red[0] + red[1] + red[2] + red[3];
}

// v_hat[b,d] = sum_v sv[b,v] * V[b,v,d]
__global__ __launch_bounds__(256) void vhat_k(const float* __restrict__ sv,
                                              const float* __restrict__ V,
                                              float* __restrict__ out) {
    int b = blockIdx.y;
    int d = blockIdx.x * 256 + threadIdx.x;
    const float* Vb = V + (size_t)b * NV * VD;
    const float* svb = sv + b * NV;
    float acc = 0.f;
    for (int v = 0; v < NV; v++) acc += svb[v] * Vb[(size_t)v * VD + d];
    out[b * VD + d] = acc;
}

// q_hat[b,d] = sum_q sq[b,q] * Q[b,q,d]   (out already offset to q_hat base)
__global__ __launch_bounds__(256) void qhat_k(const float* __restrict__ sq,
                                              const float* __restrict__ Q,
                                              float* __restrict__ out) {
    int b = blockIdx.y;
    int d = blockIdx.x * 256 + threadIdx.x;
    const float* Qb = Q + (size_t)b * NQ * QD;
    const float* sqb = sq + b * NQ;
    float acc = 0.f;
    for (int q = 0; q < NQ; q++) acc += sqb[q] * Qb[(size_t)q * QD + d];
    out[b * QD + d] = acc;
}

extern "C" void kernel_launch(void* const* d_in, const int* in_sizes, int n_in,
                              void* d_out, int out_size, void* d_ws, size_t ws_size,
                              hipStream_t stream) {
    const float* V    = (const float*)d_in[0];
    const float* Q    = (const float*)d_in[1];
    const float* Wq_w = (const float*)d_in[2];
    const float* Wq_b = (const float*)d_in[3];
    const float* Wv_w = (const float*)d_in[4];
    const float* Wv_b = (const float*)d_in[5];
    float* out = (float*)d_out;

    // workspace layout
    const size_t nQp = (size_t)B_SZ * NQ * HIDD;   // 16,777,216
    const size_t nVp = (size_t)B_SZ * NV * HIDD;   // 33,554,432
    const size_t nE  = (size_t)B_SZ * NQ * NV;     // 33,554,432
    __bf16* Qp = (__bf16*)d_ws;
    __bf16* Vp = Qp + nQp;
    __bf16* E  = Vp + nVp;
    float* R   = (float*)(E + nE);                 // B*NQ
    float* C   = R + (size_t)B_SZ * NQ;            // B*NV
    float* sv  = C + (size_t)B_SZ * NV;            // B*NV
    float* sq  = sv + (size_t)B_SZ * NV;           // B*NQ
    size_t need = (nQp + nVp + nE) * 2 +
                  ((size_t)B_SZ * (NQ + NV) * 2) * 4;
    if (ws_size < need) return;  // workspace too small -> clean failure

    // zero R and C (contiguous) for atomic accumulation
    hipMemsetAsync(R, 0, (size_t)B_SZ * (NQ + NV) * sizeof(float), stream);

    // projections
    gemm_proj<<<dim3((B_SZ * NQ) / 64, HIDD / 64), 256, 0, stream>>>(
        Q, Wq_w, Wq_b, Qp, B_SZ * NQ, HIDD, QD);
    gemm_proj<<<dim3((B_SZ * NV) / 64, HIDD / 64), 256, 0, stream>>>(
        V, Wv_w, Wv_b, Vp, B_SZ * NV, HIDD, VD);

    // E = exp(tanh(Qp Vp^T)), row/col sums
    gemm_h<<<dim3(NV / 64, NQ / 64, B_SZ), 256, 0, stream>>>(Qp, Vp, E, R, C);

    // R,C -> reciprocals in place
    recip_k<<<(B_SZ * (NQ + NV) + 255) / 256, 256, 0, stream>>>(R, B_SZ * (NQ + NV));

    // marginals
    sv_k<<<dim3(NV / 256, B_SZ), 256, 0, stream>>>(E, R, sv);
    sq_k<<<dim3(NQ, B_SZ), 256, 0, stream>>>(E, C, sq);

    // outputs
    vhat_k<<<dim3(VD / 256, B_SZ), 256, 0, stream>>>(sv, V, out);
    qhat_k<<<dim3(QD / 256, B_SZ), 256, 0, stream>>>(sq, Q, out + (size_t)B_SZ * VD);
}

// Round 3
// 636.744 us; speedup vs baseline: 1.2020x; 1.2020x over previous
//
#include <hip/hip_runtime.h>
#include <hip/hip_bf16.h>
#include <math.h>

#define B_SZ 64
#define NQ   512
#define NV   1024
#define QD   768
#define VD   512
#define HIDD 512

typedef __bf16 bf16x8 __attribute__((ext_vector_type(8)));
typedef __bf16 bf16x4 __attribute__((ext_vector_type(4)));
typedef float  floatx4 __attribute__((ext_vector_type(4)));

// ---------------------------------------------------------------------------
// fp32 -> bf16 convert (for the tiny weight matrices)
__global__ __launch_bounds__(256) void cvt_k(const float* __restrict__ s,
                                             __bf16* __restrict__ d, int n4) {
    int i = blockIdx.x * 256 + threadIdx.x;
    if (i < n4) {
        float4 f = *(const float4*)(s + (size_t)i * 4);
        bf16x4 o;
        o[0] = (__bf16)f.x; o[1] = (__bf16)f.y; o[2] = (__bf16)f.z; o[3] = (__bf16)f.w;
        *(bf16x4*)(d + (size_t)i * 4) = o;
    }
}

// ---------------------------------------------------------------------------
// Projection GEMM: C[M,512] = A[M,K] @ W[512,K]^T + bias, A fp32, W bf16.
// Block = 512 threads (8 waves), 64 rows of A, ALL 512 cols.
// A panel converted to bf16 and RESIDENT in LDS -> A read from HBM exactly once.
// W streamed from L2 via double-buffered LDS tile (256 cols x 32 k).
template<int K>
__global__ __launch_bounds__(512) void gemm_proj(
    const float* __restrict__ A, const __bf16* __restrict__ Wb,
    const float* __restrict__ bias, __bf16* __restrict__ Cout)
{
    constexpr int KS  = K / 32;       // k-steps per n-tile
    constexpr int S   = 2 * KS;       // 2 n-tiles of 256 cols
    constexpr int LDA = K + 8;        // +8 bf16 pad: row step = 4 banks
    __shared__ __bf16 As[64 * LDA];
    __shared__ __bf16 Bs[2][256 * 32];

    const int t    = threadIdx.x;
    const int lane = t & 63;
    const int wave = t >> 6;          // 0..7
    const int wn   = wave * 32;
    const int fr   = lane & 15;
    const int quad = lane >> 4;
    const int fo   = quad * 8;
    const int tile_m = blockIdx.x * 64;

    // ---- stage A panel fp32 -> bf16 -> LDS (once) ----
    {
        const int arow = t >> 3;               // 0..63
        const int ac0  = (t & 7) * 8;          // 0..56
        const float* ap = A + (size_t)(tile_m + arow) * K + ac0;
        __bf16* as = &As[arow * LDA + ac0];
        #pragma unroll
        for (int c = 0; c < K / 64; c++) {
            float4 f0 = *(const float4*)(ap + c * 64);
            float4 f1 = *(const float4*)(ap + c * 64 + 4);
            bf16x8 pk;
            pk[0] = (__bf16)f0.x; pk[1] = (__bf16)f0.y; pk[2] = (__bf16)f0.z; pk[3] = (__bf16)f0.w;
            pk[4] = (__bf16)f1.x; pk[5] = (__bf16)f1.y; pk[6] = (__bf16)f1.z; pk[7] = (__bf16)f1.w;
            *(bf16x8*)(as + c * 64) = pk;
        }
    }

    // ---- W stream, double-buffered ----
    const int wrow = t >> 1;          // 0..255
    const int wk   = (t & 1) * 16;
    bf16x8 w0, w1;
    auto loadW = [&](int s) {
        int nt = s / KS, k0 = (s % KS) * 32;
        const __bf16* wp = Wb + (size_t)(nt * 256 + wrow) * K + k0 + wk;
        w0 = *(const bf16x8*)wp;
        w1 = *(const bf16x8*)(wp + 8);
    };
    auto writeW = [&](int buf) {
        *(bf16x8*)&Bs[buf][wrow * 32 + wk]     = w0;
        *(bf16x8*)&Bs[buf][wrow * 32 + wk + 8] = w1;
    };

    loadW(0);
    writeW(0);
    __syncthreads();                  // covers A staging too

    floatx4 acc[4][2] = {};
    for (int s = 0; s < S; s++) {
        const int k0 = (s % KS) * 32;
        if (s + 1 < S) loadW(s + 1);  // global loads in flight over compute
        bf16x8 af[4], bfr[2];
        #pragma unroll
        for (int i = 0; i < 4; i++)
            af[i] = *(const bf16x8*)&As[(16 * i + fr) * LDA + k0 + fo];
        #pragma unroll
        for (int j = 0; j < 2; j++)
            bfr[j] = *(const bf16x8*)&Bs[s & 1][(wn + 16 * j + fr) * 32 + fo];
        #pragma unroll
        for (int i = 0; i < 4; i++)
            #pragma unroll
            for (int j = 0; j < 2; j++)
                acc[i][j] = __builtin_amdgcn_mfma_f32_16x16x32_bf16(af[i], bfr[j], acc[i][j], 0, 0, 0);
        if (s + 1 < S) writeW((s + 1) & 1);   // buffer not read this step
        __syncthreads();
        if ((s % KS) == KS - 1) {     // end of an n-tile: epilogue, reset acc
            const int nt = s / KS;
            #pragma unroll
            for (int j = 0; j < 2; j++) {
                const int col = nt * 256 + wn + 16 * j + fr;
                const float bv = bias[col];
                #pragma unroll
                for (int i = 0; i < 4; i++)
                    #pragma unroll
                    for (int r = 0; r < 4; r++) {
                        const int row = tile_m + 16 * i + quad * 4 + r;
                        Cout[(size_t)row * HIDD + col] = (__bf16)(acc[i][j][r] + bv);
                        acc[i][j][r] = 0.f;
                    }
            }
        }
    }
}

// ---------------------------------------------------------------------------
// Per batch: S = Qp[b] @ Vp[b]^T (128x128 tile); E = exp(tanh(S)) -> Eg bf16;
// row sums -> R (atomic), col sums -> C (atomic), via shfl_xor reductions.
__global__ __launch_bounds__(256) void gemm_h(
    const __bf16* __restrict__ Qp, const __bf16* __restrict__ Vp,
    __bf16* __restrict__ Eg, float* __restrict__ R, float* __restrict__ Csum)
{
    __shared__ __bf16 As[128 * 32];
    __shared__ __bf16 Bs[128 * 32];
    const int b      = blockIdx.z;
    const int tile_q = blockIdx.y * 128;
    const int tile_v = blockIdx.x * 128;
    const int t    = threadIdx.x;
    const int lane = t & 63;
    const int wave = t >> 6;
    const int wm = (wave >> 1) * 64;
    const int wn = (wave & 1) * 64;
    const int fr   = lane & 15;
    const int quad = lane >> 4;
    const int fo   = quad * 8;
    const int srow = t >> 2;          // 0..63 (handles srow and srow+64)
    const int sk   = (t & 3) * 8;

    const __bf16* Aq = Qp + ((size_t)b * NQ + tile_q + srow) * HIDD + sk;
    const __bf16* Bv = Vp + ((size_t)b * NV + tile_v + srow) * HIDD + sk;
    const size_t half = (size_t)64 * HIDD;

    floatx4 acc[4][4] = {};
    for (int k0 = 0; k0 < HIDD; k0 += 32) {
        *(bf16x8*)&As[srow * 32 + sk]        = *(const bf16x8*)(Aq + k0);
        *(bf16x8*)&As[(srow + 64) * 32 + sk] = *(const bf16x8*)(Aq + half + k0);
        *(bf16x8*)&Bs[srow * 32 + sk]        = *(const bf16x8*)(Bv + k0);
        *(bf16x8*)&Bs[(srow + 64) * 32 + sk] = *(const bf16x8*)(Bv + half + k0);
        __syncthreads();
        bf16x8 af[4], bfr[4];
        #pragma unroll
        for (int i = 0; i < 4; i++)
            af[i] = *(const bf16x8*)&As[(wm + 16 * i + fr) * 32 + fo];
        #pragma unroll
        for (int j = 0; j < 4; j++)
            bfr[j] = *(const bf16x8*)&Bs[(wn + 16 * j + fr) * 32 + fo];
        #pragma unroll
        for (int i = 0; i < 4; i++)
            #pragma unroll
            for (int j = 0; j < 4; j++)
                acc[i][j] = __builtin_amdgcn_mfma_f32_16x16x32_bf16(af[i], bfr[j], acc[i][j], 0, 0, 0);
        __syncthreads();
    }

    // epilogue: e = exp(tanh(s)) in-register
    #pragma unroll
    for (int i = 0; i < 4; i++)
        #pragma unroll
        for (int j = 0; j < 4; j++)
            #pragma unroll
            for (int r = 0; r < 4; r++)
                acc[i][j][r] = __expf(tanhf(acc[i][j][r]));

    // store E (bf16)
    #pragma unroll
    for (int i = 0; i < 4; i++)
        #pragma unroll
        for (int r = 0; r < 4; r++) {
            const size_t rowbase =
                ((size_t)b * NQ + tile_q + wm + 16 * i + quad * 4 + r) * NV + tile_v;
            #pragma unroll
            for (int j = 0; j < 4; j++)
                Eg[rowbase + wn + 16 * j + fr] = (__bf16)acc[i][j][r];
        }

    // row sums over this wave's 64 cols: reduce across fr (lanes xor 1,2,4,8)
    float rs[4][4];
    #pragma unroll
    for (int i = 0; i < 4; i++)
        #pragma unroll
        for (int r = 0; r < 4; r++) {
            float s = acc[i][0][r] + acc[i][1][r] + acc[i][2][r] + acc[i][3][r];
            s += __shfl_xor(s, 1); s += __shfl_xor(s, 2);
            s += __shfl_xor(s, 4); s += __shfl_xor(s, 8);
            rs[i][r] = s;
        }
    if (fr == 0) {
        #pragma unroll
        for (int i = 0; i < 4; i++)
            #pragma unroll
            for (int r = 0; r < 4; r++)
                atomicAdd(&R[b * NQ + tile_q + wm + 16 * i + quad * 4 + r], rs[i][r]);
    }

    // col sums over this wave's 64 rows: reduce across quad (lanes xor 16,32)
    float cs[4];
    #pragma unroll
    for (int j = 0; j < 4; j++) {
        float s = 0.f;
        #pragma unroll
        for (int i = 0; i < 4; i++)
            #pragma unroll
            for (int r = 0; r < 4; r++)
                s += acc[i][j][r];
        s += __shfl_xor(s, 16); s += __shfl_xor(s, 32);
        cs[j] = s;
    }
    if (quad == 0) {
        #pragma unroll
        for (int j = 0; j < 4; j++)
            atomicAdd(&Csum[b * NV + tile_v + wn + 16 * j + fr], cs[j]);
    }
}

// ---------------------------------------------------------------------------
__global__ __launch_bounds__(256) void recip_k(float* __restrict__ p, int n) {
    int i = blockIdx.x * 256 + threadIdx.x;
    if (i < n) p[i] = 1.0f / p[i];
}

// One E pass computes both marginals:
//   sv[b,v] = sum_q E[b,q,v]*Rinv[b,q]   (atomic partials)
//   sq[b,q] = sum_v E[b,q,v]*Cinv[b,v]   (wave-exclusive rows, direct write)
__global__ __launch_bounds__(256) void marg_k(
    const __bf16* __restrict__ E, const float* __restrict__ Rinv,
    const float* __restrict__ Cinv, float* __restrict__ sv,
    float* __restrict__ sq)
{
    const int b  = blockIdx.y;
    const int q0 = blockIdx.x * 64;
    const int t = threadIdx.x, lane = t & 63, wave = t >> 6;
    const float* Ci = Cinv + b * NV;
    float ci[4][4];
    float svp[4][4] = {};
    #pragma unroll
    for (int c = 0; c < 4; c++)
        *(float4*)ci[c] = *(const float4*)&Ci[c * 256 + lane * 4];
    const float* Ri = Rinv + b * NQ + q0;
    for (int rr = 0; rr < 16; rr++) {
        const int q = wave * 16 + rr;
        const __bf16* Erow = E + ((size_t)b * NQ + q0 + q) * NV;
        const float ri = Ri[q];
        float p = 0.f;
        #pragma unroll
        for (int c = 0; c < 4; c++) {
            bf16x4 ev = *(const bf16x4*)&Erow[c * 256 + lane * 4];
            #pragma unroll
            for (int k = 0; k < 4; k++) {
                float e = (float)ev[k];
                svp[c][k] += e * ri;
                p += e * ci[c][k];
            }
        }
        #pragma unroll
        for (int m = 1; m < 64; m <<= 1) p += __shfl_xor(p, m);
        if (lane == 0) sq[b * NQ + q0 + q] = p;
    }
    #pragma unroll
    for (int c = 0; c < 4; c++)
        #pragma unroll
        for (int k = 0; k < 4; k++)
            atomicAdd(&sv[b * NV + c * 256 + lane * 4 + k], svp[c][k]);
}

// v_hat[b,d] += sum_{v in chunk} sv[b,v] * V[b,v,d]
__global__ __launch_bounds__(256) void vhat_k(const float* __restrict__ sv,
                                              const float* __restrict__ V,
                                              float* __restrict__ out) {
    const int b  = blockIdx.y;
    const int v0 = blockIdx.z * 256;
    const int d  = blockIdx.x * 256 + threadIdx.x;
    const float* Vb  = V + ((size_t)b * NV + v0) * VD + d;
    const float* svb = sv + b * NV + v0;
    float acc = 0.f;
    for (int v = 0; v < 256; v++) acc += svb[v] * Vb[(size_t)v * VD];
    atomicAdd(&out[b * VD + d], acc);
}

// q_hat[b,d] += sum_{q in chunk} sq[b,q] * Q[b,q,d]  (out pre-offset)
__global__ __launch_bounds__(256) void qhat_k(const float* __restrict__ sq,
                                              const float* __restrict__ Q,
                                              float* __restrict__ out) {
    const int b  = blockIdx.y;
    const int q0 = blockIdx.z * 256;
    const int d  = blockIdx.x * 256 + threadIdx.x;
    const float* Qb  = Q + ((size_t)b * NQ + q0) * QD + d;
    const float* sqb = sq + b * NQ + q0;
    float acc = 0.f;
    for (int q = 0; q < 256; q++) acc += sqb[q] * Qb[(size_t)q * QD];
    atomicAdd(&out[b * QD + d], acc);
}

// ---------------------------------------------------------------------------
extern "C" void kernel_launch(void* const* d_in, const int* in_sizes, int n_in,
                              void* d_out, int out_size, void* d_ws, size_t ws_size,
                              hipStream_t stream) {
    const float* V    = (const float*)d_in[0];
    const float* Q    = (const float*)d_in[1];
    const float* Wq_w = (const float*)d_in[2];
    const float* Wq_b = (const float*)d_in[3];
    const float* Wv_w = (const float*)d_in[4];
    const float* Wv_b = (const float*)d_in[5];
    float* out = (float*)d_out;

    const size_t nQp = (size_t)B_SZ * NQ * HIDD;
    const size_t nVp = (size_t)B_SZ * NV * HIDD;
    const size_t nE  = (size_t)B_SZ * NQ * NV;
    const size_t nWq = (size_t)HIDD * QD;
    const size_t nWv = (size_t)HIDD * VD;
    __bf16* Qp = (__bf16*)d_ws;
    __bf16* Vp = Qp + nQp;
    __bf16* E  = Vp + nVp;
    float* R   = (float*)(E + nE);                 // B*NQ
    float* C   = R + (size_t)B_SZ * NQ;            // B*NV
    float* sv  = C + (size_t)B_SZ * NV;            // B*NV
    float* sq  = sv + (size_t)B_SZ * NV;           // B*NQ
    __bf16* Wq = (__bf16*)(sq + (size_t)B_SZ * NQ);
    __bf16* Wv = Wq + nWq;
    size_t need = (nQp + nVp + nE + nWq + nWv) * 2 +
                  ((size_t)B_SZ * (NQ + NV) * 2) * 4;
    if (ws_size < need) return;

    // zero R, C, sv, sq (contiguous) and the output (atomic accumulation)
    hipMemsetAsync(R, 0, (size_t)B_SZ * (NQ + NV) * 2 * sizeof(float), stream);
    hipMemsetAsync(d_out, 0, (size_t)out_size * sizeof(float), stream);

    // weights -> bf16
    cvt_k<<<(int)(nWq / 1024), 256, 0, stream>>>(Wq_w, Wq, (int)(nWq / 4));
    cvt_k<<<(int)(nWv / 1024), 256, 0, stream>>>(Wv_w, Wv, (int)(nWv / 4));

    // projections (A read once; LDS-resident panel)
    gemm_proj<QD><<<(B_SZ * NQ) / 64, 512, 0, stream>>>(Q, Wq, Wq_b, Qp);
    gemm_proj<VD><<<(B_SZ * NV) / 64, 512, 0, stream>>>(V, Wv, Wv_b, Vp);

    // E = exp(tanh(Qp Vp^T)) + row/col sums
    gemm_h<<<dim3(NV / 128, NQ / 128, B_SZ), 256, 0, stream>>>(Qp, Vp, E, R, C);

    // reciprocals of R and C
    recip_k<<<(B_SZ * (NQ + NV) + 255) / 256, 256, 0, stream>>>(R, B_SZ * (NQ + NV));

    // fused marginals (single E pass)
    marg_k<<<dim3(NQ / 64, B_SZ), 256, 0, stream>>>(E, R, C, sv, sq);

    // outputs
    vhat_k<<<dim3(VD / 256, B_SZ, NV / 256), 256, 0, stream>>>(sv, V, out);
    qhat_k<<<dim3(QD / 256, B_SZ, NQ / 256), 256, 0, stream>>>(sq, Q, out + (size_t)B_SZ * VD);
}

// Round 4
// 590.006 us; speedup vs baseline: 1.2972x; 1.0792x over previous
//
#include <hip/hip_runtime.h>
#include <hip/hip_bf16.h>
#include <math.h>

#define B_SZ 64
#define NQ   512
#define NV   1024
#define QD   768
#define VD   512
#define HIDD 512

typedef __bf16 bf16x8 __attribute__((ext_vector_type(8)));
typedef __bf16 bf16x4 __attribute__((ext_vector_type(4)));
typedef float  floatx4 __attribute__((ext_vector_type(4)));

// async global->LDS, 16 bytes per lane; lds dest must be wave-uniform base,
// HW writes lane l at base + l*16.
__device__ __forceinline__ void g2lds16(const __bf16* g, __bf16* l) {
    __builtin_amdgcn_global_load_lds((const __attribute__((address_space(1))) void*)g,
                                     (__attribute__((address_space(3))) void*)l,
                                     16, 0, 0);
}

// exp(tanh(s)) = e^(1 - 2/(e^{2s}+1)); saturates correctly as e^{2s}->0/inf.
__device__ __forceinline__ float exptanh(float s) {
    float t = __expf(2.0f * s);
    float r = __builtin_amdgcn_rcpf(t + 1.0f);
    return __expf(1.0f - 2.0f * r);
}

// ---------------------------------------------------------------------------
// fp32 -> bf16 convert (weights)
__global__ __launch_bounds__(256) void cvt_k(const float* __restrict__ s,
                                             __bf16* __restrict__ d, int n4) {
    int i = blockIdx.x * 256 + threadIdx.x;
    if (i < n4) {
        float4 f = *(const float4*)(s + (size_t)i * 4);
        bf16x4 o;
        o[0] = (__bf16)f.x; o[1] = (__bf16)f.y; o[2] = (__bf16)f.z; o[3] = (__bf16)f.w;
        *(bf16x4*)(d + (size_t)i * 4) = o;
    }
}

// ---------------------------------------------------------------------------
// Projection GEMM: C[M,512] = A[M,K] @ W[512,K]^T + bias.
// 128x128 tile, 4 waves, acc 4x4. A fp32 staged with fused convert;
// W bf16 staged via global_load_lds (L2-resident, 0.5-0.75 MB).
template<int K>
__global__ __launch_bounds__(256) void gemm_proj(
    const float* __restrict__ A, const __bf16* __restrict__ Wb,
    const float* __restrict__ bias, __bf16* __restrict__ Cout)
{
    __shared__ __bf16 As[128 * 32];
    __shared__ __bf16 Bs[128 * 32];
    const int tile_m = blockIdx.x * 128;
    const int tile_n = blockIdx.y * 128;
    const int t = threadIdx.x, lane = t & 63, wave = t >> 6;
    const int wm = (wave >> 1) * 64, wn = (wave & 1) * 64;
    const int fr = lane & 15, quad = lane >> 4, fo = quad * 8;

    // A staging: thread -> (row = t>>1, 16 k's at (t&1)*16)
    const int arow = t >> 1, akc = (t & 1) * 16;
    const float* ap = A + (size_t)(tile_m + arow) * K + akc;
    // W async staging: wave covers rows [32w,32w+32) in 2 calls of 16 rows
    const int brow = wave * 32 + (lane >> 2);
    const int bkc  = (lane & 3) * 8;
    const __bf16* wp = Wb + (size_t)(tile_n + brow) * K + bkc;
    __bf16* bsw = &Bs[wave * 1024];

    floatx4 acc[4][4] = {};
    for (int k0 = 0; k0 < K; k0 += 32) {
        g2lds16(wp + k0, bsw);
        g2lds16(wp + (size_t)16 * K + k0, bsw + 512);
        float4 f0 = *(const float4*)(ap + k0);
        float4 f1 = *(const float4*)(ap + k0 + 4);
        float4 f2 = *(const float4*)(ap + k0 + 8);
        float4 f3 = *(const float4*)(ap + k0 + 12);
        bf16x8 p0, p1;
        p0[0] = (__bf16)f0.x; p0[1] = (__bf16)f0.y; p0[2] = (__bf16)f0.z; p0[3] = (__bf16)f0.w;
        p0[4] = (__bf16)f1.x; p0[5] = (__bf16)f1.y; p0[6] = (__bf16)f1.z; p0[7] = (__bf16)f1.w;
        p1[0] = (__bf16)f2.x; p1[1] = (__bf16)f2.y; p1[2] = (__bf16)f2.z; p1[3] = (__bf16)f2.w;
        p1[4] = (__bf16)f3.x; p1[5] = (__bf16)f3.y; p1[6] = (__bf16)f3.z; p1[7] = (__bf16)f3.w;
        *(bf16x8*)&As[arow * 32 + akc]     = p0;
        *(bf16x8*)&As[arow * 32 + akc + 8] = p1;
        __syncthreads();
        bf16x8 af[4], bg[4];
        #pragma unroll
        for (int i = 0; i < 4; i++)
            af[i] = *(const bf16x8*)&As[(wm + 16 * i + fr) * 32 + fo];
        #pragma unroll
        for (int j = 0; j < 4; j++)
            bg[j] = *(const bf16x8*)&Bs[(wn + 16 * j + fr) * 32 + fo];
        #pragma unroll
        for (int i = 0; i < 4; i++)
            #pragma unroll
            for (int j = 0; j < 4; j++)
                acc[i][j] = __builtin_amdgcn_mfma_f32_16x16x32_bf16(af[i], bg[j], acc[i][j], 0, 0, 0);
        __syncthreads();
    }
    #pragma unroll
    for (int j = 0; j < 4; j++) {
        const int col = tile_n + wn + 16 * j + fr;
        const float bv = bias[col];
        #pragma unroll
        for (int i = 0; i < 4; i++)
            #pragma unroll
            for (int r = 0; r < 4; r++) {
                const int row = tile_m + wm + 16 * i + quad * 4 + r;
                Cout[(size_t)row * HIDD + col] = (__bf16)(acc[i][j][r] + bv);
            }
    }
}

// ---------------------------------------------------------------------------
// Per batch: S = Qp[b] @ Vp[b]^T (128x128 tile, async staging);
// E = exp(tanh(S)) -> Eg bf16; row sums -> R, col sums -> C (atomics).
__global__ __launch_bounds__(256) void gemm_h(
    const __bf16* __restrict__ Qp, const __bf16* __restrict__ Vp,
    __bf16* __restrict__ Eg, float* __restrict__ R, float* __restrict__ Csum)
{
    __shared__ __bf16 As[128 * 32];
    __shared__ __bf16 Bs[128 * 32];
    const int b      = blockIdx.z;
    const int tile_q = blockIdx.y * 128;
    const int tile_v = blockIdx.x * 128;
    const int t = threadIdx.x, lane = t & 63, wave = t >> 6;
    const int wm = (wave >> 1) * 64, wn = (wave & 1) * 64;
    const int fr = lane & 15, quad = lane >> 4, fo = quad * 8;

    const int grow = wave * 32 + (lane >> 2);
    const int gk   = (lane & 3) * 8;
    const __bf16* Aq = Qp + ((size_t)b * NQ + tile_q + grow) * HIDD + gk;
    const __bf16* Bv = Vp + ((size_t)b * NV + tile_v + grow) * HIDD + gk;
    __bf16* asw = &As[wave * 1024];
    __bf16* bsw = &Bs[wave * 1024];

    floatx4 acc[4][4] = {};
    for (int k0 = 0; k0 < HIDD; k0 += 32) {
        g2lds16(Aq + k0, asw);
        g2lds16(Aq + (size_t)16 * HIDD + k0, asw + 512);
        g2lds16(Bv + k0, bsw);
        g2lds16(Bv + (size_t)16 * HIDD + k0, bsw + 512);
        __syncthreads();
        bf16x8 af[4], bg[4];
        #pragma unroll
        for (int i = 0; i < 4; i++)
            af[i] = *(const bf16x8*)&As[(wm + 16 * i + fr) * 32 + fo];
        #pragma unroll
        for (int j = 0; j < 4; j++)
            bg[j] = *(const bf16x8*)&Bs[(wn + 16 * j + fr) * 32 + fo];
        #pragma unroll
        for (int i = 0; i < 4; i++)
            #pragma unroll
            for (int j = 0; j < 4; j++)
                acc[i][j] = __builtin_amdgcn_mfma_f32_16x16x32_bf16(af[i], bg[j], acc[i][j], 0, 0, 0);
        __syncthreads();
    }

    #pragma unroll
    for (int i = 0; i < 4; i++)
        #pragma unroll
        for (int j = 0; j < 4; j++)
            #pragma unroll
            for (int r = 0; r < 4; r++)
                acc[i][j][r] = exptanh(acc[i][j][r]);

    #pragma unroll
    for (int i = 0; i < 4; i++)
        #pragma unroll
        for (int r = 0; r < 4; r++) {
            const size_t rowbase =
                ((size_t)b * NQ + tile_q + wm + 16 * i + quad * 4 + r) * NV + tile_v;
            #pragma unroll
            for (int j = 0; j < 4; j++)
                Eg[rowbase + wn + 16 * j + fr] = (__bf16)acc[i][j][r];
        }

    float rs[4][4];
    #pragma unroll
    for (int i = 0; i < 4; i++)
        #pragma unroll
        for (int r = 0; r < 4; r++) {
            float s = acc[i][0][r] + acc[i][1][r] + acc[i][2][r] + acc[i][3][r];
            s += __shfl_xor(s, 1); s += __shfl_xor(s, 2);
            s += __shfl_xor(s, 4); s += __shfl_xor(s, 8);
            rs[i][r] = s;
        }
    if (fr == 0) {
        #pragma unroll
        for (int i = 0; i < 4; i++)
            #pragma unroll
            for (int r = 0; r < 4; r++)
                atomicAdd(&R[b * NQ + tile_q + wm + 16 * i + quad * 4 + r], rs[i][r]);
    }
    float cs[4];
    #pragma unroll
    for (int j = 0; j < 4; j++) {
        float s = 0.f;
        #pragma unroll
        for (int i = 0; i < 4; i++)
            #pragma unroll
            for (int r = 0; r < 4; r++)
                s += acc[i][j][r];
        s += __shfl_xor(s, 16); s += __shfl_xor(s, 32);
        cs[j] = s;
    }
    if (quad == 0) {
        #pragma unroll
        for (int j = 0; j < 4; j++)
            atomicAdd(&Csum[b * NV + tile_v + wn + 16 * j + fr], cs[j]);
    }
}

// ---------------------------------------------------------------------------
// One E pass computes both marginals (reciprocals computed inline):
//   sv[b,v] = sum_q E[b,q,v]/R[b,q]   (atomic partials)
//   sq[b,q] = sum_v E[b,q,v]/C[b,v]   (wave-exclusive rows, direct write)
__global__ __launch_bounds__(256) void marg_k(
    const __bf16* __restrict__ E, const float* __restrict__ R,
    const float* __restrict__ C, float* __restrict__ sv,
    float* __restrict__ sq)
{
    const int b  = blockIdx.y;
    const int q0 = blockIdx.x * 64;
    const int t = threadIdx.x, lane = t & 63, wave = t >> 6;
    const float* Cb = C + b * NV;
    float ci[2][8];
    float svp[2][8] = {};
    #pragma unroll
    for (int c = 0; c < 2; c++) {
        float4 c0 = *(const float4*)&Cb[c * 512 + lane * 8];
        float4 c1 = *(const float4*)&Cb[c * 512 + lane * 8 + 4];
        ci[c][0] = 1.0f / c0.x; ci[c][1] = 1.0f / c0.y;
        ci[c][2] = 1.0f / c0.z; ci[c][3] = 1.0f / c0.w;
        ci[c][4] = 1.0f / c1.x; ci[c][5] = 1.0f / c1.y;
        ci[c][6] = 1.0f / c1.z; ci[c][7] = 1.0f / c1.w;
    }
    const float* Rb = R + b * NQ + q0;
    for (int rr = 0; rr < 16; rr++) {
        const int q = wave * 16 + rr;
        const __bf16* Erow = E + ((size_t)b * NQ + q0 + q) * NV;
        const float ri = 1.0f / Rb[q];
        float p = 0.f;
        #pragma unroll
        for (int c = 0; c < 2; c++) {
            bf16x8 ev = *(const bf16x8*)&Erow[c * 512 + lane * 8];
            #pragma unroll
            for (int k = 0; k < 8; k++) {
                float e = (float)ev[k];
                svp[c][k] += e * ri;
                p += e * ci[c][k];
            }
        }
        p += __shfl_xor(p, 1);  p += __shfl_xor(p, 2);  p += __shfl_xor(p, 4);
        p += __shfl_xor(p, 8);  p += __shfl_xor(p, 16); p += __shfl_xor(p, 32);
        if (lane == 0) sq[b * NQ + q0 + q] = p;
    }
    #pragma unroll
    for (int c = 0; c < 2; c++)
        #pragma unroll
        for (int k = 0; k < 8; k++)
            atomicAdd(&sv[b * NV + c * 512 + lane * 8 + k], svp[c][k]);
}

// v_hat[b,d] += sum_{v chunk} sv[b,v] * V[b,v,d]
__global__ __launch_bounds__(256) void vhat_k(const float* __restrict__ sv,
                                              const float* __restrict__ V,
                                              float* __restrict__ out) {
    const int b  = blockIdx.y;
    const int v0 = blockIdx.z * 256;
    const int d  = blockIdx.x * 256 + threadIdx.x;
    const float* Vb  = V + ((size_t)b * NV + v0) * VD + d;
    const float* svb = sv + b * NV + v0;
    float acc = 0.f;
    #pragma unroll 8
    for (int v = 0; v < 256; v++) acc += svb[v] * Vb[(size_t)v * VD];
    atomicAdd(&out[b * VD + d], acc);
}

// q_hat[b,d] += sum_{q chunk} sq[b,q] * Q[b,q,d]  (out pre-offset)
__global__ __launch_bounds__(256) void qhat_k(const float* __restrict__ sq,
                                              const float* __restrict__ Q,
                                              float* __restrict__ out) {
    const int b  = blockIdx.y;
    const int q0 = blockIdx.z * 256;
    const int d  = blockIdx.x * 256 + threadIdx.x;
    const float* Qb  = Q + ((size_t)b * NQ + q0) * QD + d;
    const float* sqb = sq + b * NQ + q0;
    float acc = 0.f;
    #pragma unroll 8
    for (int q = 0; q < 256; q++) acc += sqb[q] * Qb[(size_t)q * QD];
    atomicAdd(&out[b * QD + d], acc);
}

// ---------------------------------------------------------------------------
extern "C" void kernel_launch(void* const* d_in, const int* in_sizes, int n_in,
                              void* d_out, int out_size, void* d_ws, size_t ws_size,
                              hipStream_t stream) {
    const float* V    = (const float*)d_in[0];
    const float* Q    = (const float*)d_in[1];
    const float* Wq_w = (const float*)d_in[2];
    const float* Wq_b = (const float*)d_in[3];
    const float* Wv_w = (const float*)d_in[4];
    const float* Wv_b = (const float*)d_in[5];
    float* out = (float*)d_out;

    const size_t nQp = (size_t)B_SZ * NQ * HIDD;
    const size_t nVp = (size_t)B_SZ * NV * HIDD;
    const size_t nE  = (size_t)B_SZ * NQ * NV;
    const size_t nWq = (size_t)HIDD * QD;
    const size_t nWv = (size_t)HIDD * VD;
    __bf16* Qp = (__bf16*)d_ws;
    __bf16* Vp = Qp + nQp;
    __bf16* E  = Vp + nVp;
    float* R   = (float*)(E + nE);                 // B*NQ
    float* C   = R + (size_t)B_SZ * NQ;            // B*NV
    float* sv  = C + (size_t)B_SZ * NV;            // B*NV
    float* sq  = sv + (size_t)B_SZ * NV;           // B*NQ
    __bf16* Wq = (__bf16*)(sq + (size_t)B_SZ * NQ);
    __bf16* Wv = Wq + nWq;
    size_t need = (nQp + nVp + nE + nWq + nWv) * 2 +
                  ((size_t)B_SZ * (NQ + NV) * 2) * 4;
    if (ws_size < need) return;

    hipMemsetAsync(R, 0, (size_t)B_SZ * (NQ + NV) * 2 * sizeof(float), stream);
    hipMemsetAsync(d_out, 0, (size_t)out_size * sizeof(float), stream);

    cvt_k<<<(int)(nWq / 1024), 256, 0, stream>>>(Wq_w, Wq, (int)(nWq / 4));
    cvt_k<<<(int)(nWv / 1024), 256, 0, stream>>>(Wv_w, Wv, (int)(nWv / 4));

    gemm_proj<QD><<<dim3((B_SZ * NQ) / 128, HIDD / 128), 256, 0, stream>>>(Q, Wq, Wq_b, Qp);
    gemm_proj<VD><<<dim3((B_SZ * NV) / 128, HIDD / 128), 256, 0, stream>>>(V, Wv, Wv_b, Vp);

    gemm_h<<<dim3(NV / 128, NQ / 128, B_SZ), 256, 0, stream>>>(Qp, Vp, E, R, C);

    marg_k<<<dim3(NQ / 64, B_SZ), 256, 0, stream>>>(E, R, C, sv, sq);

    vhat_k<<<dim3(VD / 256, B_SZ, NV / 256), 256, 0, stream>>>(sv, V, out);
    qhat_k<<<dim3(QD / 256, B_SZ, NQ / 256), 256, 0, stream>>>(sq, Q, out + (size_t)B_SZ * VD);
}

// Round 5
// 534.370 us; speedup vs baseline: 1.4323x; 1.1041x over previous
//
#include <hip/hip_runtime.h>
#include <hip/hip_bf16.h>
#include <math.h>

#define B_SZ 64
#define NQ   512
#define NV   1024
#define QD   768
#define VD   512
#define HIDD 512

typedef __bf16 bf16x8 __attribute__((ext_vector_type(8)));
typedef __bf16 bf16x4 __attribute__((ext_vector_type(4)));
typedef float  floatx4 __attribute__((ext_vector_type(4)));

// async global->LDS, 16 bytes per lane; lds dest wave-uniform base,
// HW writes lane l at base + l*16.
__device__ __forceinline__ void g2lds16(const __bf16* g, __bf16* l) {
    __builtin_amdgcn_global_load_lds((const __attribute__((address_space(1))) void*)g,
                                     (__attribute__((address_space(3))) void*)l,
                                     16, 0, 0);
}

// exp(tanh(s)) = e^(1 - 2/(e^{2s}+1)); saturates correctly as e^{2s}->0/inf.
__device__ __forceinline__ float exptanh(float s) {
    float t = __expf(2.0f * s);
    float r = __builtin_amdgcn_rcpf(t + 1.0f);
    return __expf(1.0f - 2.0f * r);
}

// ---------------------------------------------------------------------------
// fp32 -> bf16 convert (weights)
__global__ __launch_bounds__(256) void cvt_k(const float* __restrict__ s,
                                             __bf16* __restrict__ d, int n4) {
    int i = blockIdx.x * 256 + threadIdx.x;
    if (i < n4) {
        float4 f = *(const float4*)(s + (size_t)i * 4);
        bf16x4 o;
        o[0] = (__bf16)f.x; o[1] = (__bf16)f.y; o[2] = (__bf16)f.z; o[3] = (__bf16)f.w;
        *(bf16x4*)(d + (size_t)i * 4) = o;
    }
}

// ---------------------------------------------------------------------------
// Projection GEMM: C[M,512] = A[M,K] @ W[512,K]^T + bias.
// Block = 64 rows x ALL 512 cols -> A read from HBM exactly once (HBM-bound
// optimum). 4 waves, each 64x128 (acc 4x8). W bf16 (L2-resident) staged via
// global_load_lds; A fp32 staged with fused convert (8 elems/thread).
template<int K>
__global__ __launch_bounds__(256, 2) void gemm_proj(
    const float* __restrict__ A, const __bf16* __restrict__ Wb,
    const float* __restrict__ bias, __bf16* __restrict__ Cout)
{
    __shared__ __bf16 As[64 * 32];     // 4 KB
    __shared__ __bf16 Bs[512 * 32];    // 32 KB
    const int t = threadIdx.x, lane = t & 63, wave = t >> 6;
    const int fr = lane & 15, quad = lane >> 4, fo = quad * 8;
    const int tile_m = blockIdx.x * 64;
    const int wn = wave * 128;

    // A staging: 64 rows x 32 k fp32 -> bf16; 8 elems/thread
    const int arow = t >> 2, akc = (t & 3) * 8;
    const float* ap = A + (size_t)(tile_m + arow) * K + akc;

    // W staging: wave covers rows [128w, 128w+128) in 8 g2lds of 16 rows
    const __bf16* wsrc = Wb + (size_t)(wave * 128 + (lane >> 2)) * K + (lane & 3) * 8;
    __bf16* bbase = &Bs[wave * 128 * 32];

    floatx4 acc[4][8] = {};
    for (int k0 = 0; k0 < K; k0 += 32) {
        #pragma unroll
        for (int c = 0; c < 8; c++)
            g2lds16(wsrc + (size_t)(c * 16) * K + k0, bbase + c * 512);
        float4 f0 = *(const float4*)(ap + k0);
        float4 f1 = *(const float4*)(ap + k0 + 4);
        bf16x8 p;
        p[0] = (__bf16)f0.x; p[1] = (__bf16)f0.y; p[2] = (__bf16)f0.z; p[3] = (__bf16)f0.w;
        p[4] = (__bf16)f1.x; p[5] = (__bf16)f1.y; p[6] = (__bf16)f1.z; p[7] = (__bf16)f1.w;
        *(bf16x8*)&As[arow * 32 + akc] = p;
        __syncthreads();
        bf16x8 af[4];
        #pragma unroll
        for (int i = 0; i < 4; i++)
            af[i] = *(const bf16x8*)&As[(16 * i + fr) * 32 + fo];
        #pragma unroll
        for (int j = 0; j < 8; j++) {
            bf16x8 bg = *(const bf16x8*)&Bs[(wn + 16 * j + fr) * 32 + fo];
            #pragma unroll
            for (int i = 0; i < 4; i++)
                acc[i][j] = __builtin_amdgcn_mfma_f32_16x16x32_bf16(af[i], bg, acc[i][j], 0, 0, 0);
        }
        __syncthreads();
    }
    #pragma unroll
    for (int j = 0; j < 8; j++) {
        const int col = wn + 16 * j + fr;
        const float bv = bias[col];
        #pragma unroll
        for (int i = 0; i < 4; i++)
            #pragma unroll
            for (int r = 0; r < 4; r++) {
                const int row = tile_m + 16 * i + quad * 4 + r;
                Cout[(size_t)row * HIDD + col] = (__bf16)(acc[i][j][r] + bv);
            }
    }
}

// ---------------------------------------------------------------------------
// Per batch: S = Qp[b] @ Vp[b]^T (128x128 tile, async staging);
// E = exp(tanh(S)) -> Eg bf16; row sums -> R, col sums -> C (atomics).
__global__ __launch_bounds__(256) void gemm_h(
    const __bf16* __restrict__ Qp, const __bf16* __restrict__ Vp,
    __bf16* __restrict__ Eg, float* __restrict__ R, float* __restrict__ Csum)
{
    __shared__ __bf16 As[128 * 32];
    __shared__ __bf16 Bs[128 * 32];
    const int b      = blockIdx.z;
    const int tile_q = blockIdx.y * 128;
    const int tile_v = blockIdx.x * 128;
    const int t = threadIdx.x, lane = t & 63, wave = t >> 6;
    const int wm = (wave >> 1) * 64, wn = (wave & 1) * 64;
    const int fr = lane & 15, quad = lane >> 4, fo = quad * 8;

    const int grow = wave * 32 + (lane >> 2);
    const int gk   = (lane & 3) * 8;
    const __bf16* Aq = Qp + ((size_t)b * NQ + tile_q + grow) * HIDD + gk;
    const __bf16* Bv = Vp + ((size_t)b * NV + tile_v + grow) * HIDD + gk;
    __bf16* asw = &As[wave * 1024];
    __bf16* bsw = &Bs[wave * 1024];

    floatx4 acc[4][4] = {};
    for (int k0 = 0; k0 < HIDD; k0 += 32) {
        g2lds16(Aq + k0, asw);
        g2lds16(Aq + (size_t)16 * HIDD + k0, asw + 512);
        g2lds16(Bv + k0, bsw);
        g2lds16(Bv + (size_t)16 * HIDD + k0, bsw + 512);
        __syncthreads();
        bf16x8 af[4], bg[4];
        #pragma unroll
        for (int i = 0; i < 4; i++)
            af[i] = *(const bf16x8*)&As[(wm + 16 * i + fr) * 32 + fo];
        #pragma unroll
        for (int j = 0; j < 4; j++)
            bg[j] = *(const bf16x8*)&Bs[(wn + 16 * j + fr) * 32 + fo];
        #pragma unroll
        for (int i = 0; i < 4; i++)
            #pragma unroll
            for (int j = 0; j < 4; j++)
                acc[i][j] = __builtin_amdgcn_mfma_f32_16x16x32_bf16(af[i], bg[j], acc[i][j], 0, 0, 0);
        __syncthreads();
    }

    #pragma unroll
    for (int i = 0; i < 4; i++)
        #pragma unroll
        for (int j = 0; j < 4; j++)
            #pragma unroll
            for (int r = 0; r < 4; r++)
                acc[i][j][r] = exptanh(acc[i][j][r]);

    #pragma unroll
    for (int i = 0; i < 4; i++)
        #pragma unroll
        for (int r = 0; r < 4; r++) {
            const size_t rowbase =
                ((size_t)b * NQ + tile_q + wm + 16 * i + quad * 4 + r) * NV + tile_v;
            #pragma unroll
            for (int j = 0; j < 4; j++)
                Eg[rowbase + wn + 16 * j + fr] = (__bf16)acc[i][j][r];
        }

    float rs[4][4];
    #pragma unroll
    for (int i = 0; i < 4; i++)
        #pragma unroll
        for (int r = 0; r < 4; r++) {
            float s = acc[i][0][r] + acc[i][1][r] + acc[i][2][r] + acc[i][3][r];
            s += __shfl_xor(s, 1); s += __shfl_xor(s, 2);
            s += __shfl_xor(s, 4); s += __shfl_xor(s, 8);
            rs[i][r] = s;
        }
    if (fr == 0) {
        #pragma unroll
        for (int i = 0; i < 4; i++)
            #pragma unroll
            for (int r = 0; r < 4; r++)
                atomicAdd(&R[b * NQ + tile_q + wm + 16 * i + quad * 4 + r], rs[i][r]);
    }
    float cs[4];
    #pragma unroll
    for (int j = 0; j < 4; j++) {
        float s = 0.f;
        #pragma unroll
        for (int i = 0; i < 4; i++)
            #pragma unroll
            for (int r = 0; r < 4; r++)
                s += acc[i][j][r];
        s += __shfl_xor(s, 16); s += __shfl_xor(s, 32);
        cs[j] = s;
    }
    if (quad == 0) {
        #pragma unroll
        for (int j = 0; j < 4; j++)
            atomicAdd(&Csum[b * NV + tile_v + wn + 16 * j + fr], cs[j]);
    }
}

// ---------------------------------------------------------------------------
// One E pass computes both marginals (reciprocals computed inline):
//   sv[b,v] = sum_q E[b,q,v]/R[b,q]   (atomic partials)
//   sq[b,q] = sum_v E[b,q,v]/C[b,v]   (wave-exclusive rows, direct write)
__global__ __launch_bounds__(256) void marg_k(
    const __bf16* __restrict__ E, const float* __restrict__ R,
    const float* __restrict__ C, float* __restrict__ sv,
    float* __restrict__ sq)
{
    const int b  = blockIdx.y;
    const int q0 = blockIdx.x * 64;
    const int t = threadIdx.x, lane = t & 63, wave = t >> 6;
    const float* Cb = C + b * NV;
    float ci[2][8];
    float svp[2][8] = {};
    #pragma unroll
    for (int c = 0; c < 2; c++) {
        float4 c0 = *(const float4*)&Cb[c * 512 + lane * 8];
        float4 c1 = *(const float4*)&Cb[c * 512 + lane * 8 + 4];
        ci[c][0] = 1.0f / c0.x; ci[c][1] = 1.0f / c0.y;
        ci[c][2] = 1.0f / c0.z; ci[c][3] = 1.0f / c0.w;
        ci[c][4] = 1.0f / c1.x; ci[c][5] = 1.0f / c1.y;
        ci[c][6] = 1.0f / c1.z; ci[c][7] = 1.0f / c1.w;
    }
    const float* Rb = R + b * NQ + q0;
    for (int rr = 0; rr < 16; rr++) {
        const int q = wave * 16 + rr;
        const __bf16* Erow = E + ((size_t)b * NQ + q0 + q) * NV;
        const float ri = 1.0f / Rb[q];
        float p = 0.f;
        #pragma unroll
        for (int c = 0; c < 2; c++) {
            bf16x8 ev = *(const bf16x8*)&Erow[c * 512 + lane * 8];
            #pragma unroll
            for (int k = 0; k < 8; k++) {
                float e = (float)ev[k];
                svp[c][k] += e * ri;
                p += e * ci[c][k];
            }
        }
        p += __shfl_xor(p, 1);  p += __shfl_xor(p, 2);  p += __shfl_xor(p, 4);
        p += __shfl_xor(p, 8);  p += __shfl_xor(p, 16); p += __shfl_xor(p, 32);
        if (lane == 0) sq[b * NQ + q0 + q] = p;
    }
    #pragma unroll
    for (int c = 0; c < 2; c++)
        #pragma unroll
        for (int k = 0; k < 8; k++)
            atomicAdd(&sv[b * NV + c * 512 + lane * 8 + k], svp[c][k]);
}

// v_hat[b,d] += sum_{v chunk} sv[b,v] * V[b,v,d]
__global__ __launch_bounds__(256) void vhat_k(const float* __restrict__ sv,
                                              const float* __restrict__ V,
                                              float* __restrict__ out) {
    const int b  = blockIdx.y;
    const int v0 = blockIdx.z * 256;
    const int d  = blockIdx.x * 256 + threadIdx.x;
    const float* Vb  = V + ((size_t)b * NV + v0) * VD + d;
    const float* svb = sv + b * NV + v0;
    float acc = 0.f;
    #pragma unroll 8
    for (int v = 0; v < 256; v++) acc += svb[v] * Vb[(size_t)v * VD];
    atomicAdd(&out[b * VD + d], acc);
}

// q_hat[b,d] += sum_{q chunk} sq[b,q] * Q[b,q,d]  (out pre-offset)
__global__ __launch_bounds__(256) void qhat_k(const float* __restrict__ sq,
                                              const float* __restrict__ Q,
                                              float* __restrict__ out) {
    const int b  = blockIdx.y;
    const int q0 = blockIdx.z * 256;
    const int d  = blockIdx.x * 256 + threadIdx.x;
    const float* Qb  = Q + ((size_t)b * NQ + q0) * QD + d;
    const float* sqb = sq + b * NQ + q0;
    float acc = 0.f;
    #pragma unroll 8
    for (int q = 0; q < 256; q++) acc += sqb[q] * Qb[(size_t)q * QD];
    atomicAdd(&out[b * QD + d], acc);
}

// ---------------------------------------------------------------------------
extern "C" void kernel_launch(void* const* d_in, const int* in_sizes, int n_in,
                              void* d_out, int out_size, void* d_ws, size_t ws_size,
                              hipStream_t stream) {
    const float* V    = (const float*)d_in[0];
    const float* Q    = (const float*)d_in[1];
    const float* Wq_w = (const float*)d_in[2];
    const float* Wq_b = (const float*)d_in[3];
    const float* Wv_w = (const float*)d_in[4];
    const float* Wv_b = (const float*)d_in[5];
    float* out = (float*)d_out;

    const size_t nQp = (size_t)B_SZ * NQ * HIDD;
    const size_t nVp = (size_t)B_SZ * NV * HIDD;
    const size_t nE  = (size_t)B_SZ * NQ * NV;
    const size_t nWq = (size_t)HIDD * QD;
    const size_t nWv = (size_t)HIDD * VD;
    __bf16* Qp = (__bf16*)d_ws;
    __bf16* Vp = Qp + nQp;
    __bf16* E  = Vp + nVp;
    float* R   = (float*)(E + nE);                 // B*NQ
    float* C   = R + (size_t)B_SZ * NQ;            // B*NV
    float* sv  = C + (size_t)B_SZ * NV;            // B*NV
    float* sq  = sv + (size_t)B_SZ * NV;           // B*NQ
    __bf16* Wq = (__bf16*)(sq + (size_t)B_SZ * NQ);
    __bf16* Wv = Wq + nWq;
    size_t need = (nQp + nVp + nE + nWq + nWv) * 2 +
                  ((size_t)B_SZ * (NQ + NV) * 2) * 4;
    if (ws_size < need) return;

    hipMemsetAsync(R, 0, (size_t)B_SZ * (NQ + NV) * 2 * sizeof(float), stream);
    hipMemsetAsync(d_out, 0, (size_t)out_size * sizeof(float), stream);

    cvt_k<<<(int)(nWq / 1024), 256, 0, stream>>>(Wq_w, Wq, (int)(nWq / 4));
    cvt_k<<<(int)(nWv / 1024), 256, 0, stream>>>(Wv_w, Wv, (int)(nWv / 4));

    gemm_proj<QD><<<(B_SZ * NQ) / 64, 256, 0, stream>>>(Q, Wq, Wq_b, Qp);
    gemm_proj<VD><<<(B_SZ * NV) / 64, 256, 0, stream>>>(V, Wv, Wv_b, Vp);

    gemm_h<<<dim3(NV / 128, NQ / 128, B_SZ), 256, 0, stream>>>(Qp, Vp, E, R, C);

    marg_k<<<dim3(NQ / 64, B_SZ), 256, 0, stream>>>(E, R, C, sv, sq);

    vhat_k<<<dim3(VD / 256, B_SZ, NV / 256), 256, 0, stream>>>(sv, V, out);
    qhat_k<<<dim3(QD / 256, B_SZ, NQ / 256), 256, 0, stream>>>(sq, Q, out + (size_t)B_SZ * VD);
}